// Round 10
// baseline (1179.677 us; speedup 1.0000x reference)
//
#include <hip/hip_runtime.h>

#define NN 100000
#define NE 1600000
#define HC 256
#define NBUCK 196    // ceil(NN/512) buckets of 512 dsts

typedef __attribute__((ext_vector_type(8))) short short8;
typedef __attribute__((ext_vector_type(4))) float f32x4;

__device__ __forceinline__ float4 ld4(const float* p) { return *(const float4*)p; }
__device__ __forceinline__ unsigned short f2bf(float f) {
    unsigned u = __float_as_uint(f);
    return (unsigned short)((u + 0x7fffu + ((u >> 16) & 1u)) >> 16);
}
__device__ __forceinline__ float bf2f(unsigned short h) { return __uint_as_float(((unsigned)h) << 16); }

// unpack 8 bf16 (uint4) -> 8 f32
__device__ __forceinline__ void unpack8(uint4 v, float* f) {
    f[0] = __uint_as_float(v.x << 16); f[1] = __uint_as_float(v.x & 0xffff0000u);
    f[2] = __uint_as_float(v.y << 16); f[3] = __uint_as_float(v.y & 0xffff0000u);
    f[4] = __uint_as_float(v.z << 16); f[5] = __uint_as_float(v.z & 0xffff0000u);
    f[6] = __uint_as_float(v.w << 16); f[7] = __uint_as_float(v.w & 0xffff0000u);
}

// ---------------- CSR build: bucketed two-pass sort --------------------------
// Pass A1: coarse histogram (LDS pre-aggregated)
__global__ __launch_bounds__(256) void k_bhist(const int* __restrict__ dst,
                                               int* __restrict__ bhist) {
    __shared__ int h[NBUCK];
    int t = threadIdx.x;
    for (int j = t; j < NBUCK; j += 256) h[j] = 0;
    __syncthreads();
    int base = blockIdx.x * 2048;
    int lim = min(base + 2048, NE);
    for (int i = base + t; i < lim; i += 256)
        atomicAdd(&h[dst[i] >> 9], 1);
    __syncthreads();
    for (int j = t; j < NBUCK; j += 256) if (h[j]) atomicAdd(&bhist[j], h[j]);
}

// Pass A2: scan 196 bucket counts
__global__ void k_bscan(const int* __restrict__ bhist, int* __restrict__ boffs,
                        int* __restrict__ bcursor, int* __restrict__ offs) {
    __shared__ int sh[256];
    int t = threadIdx.x;
    int v = (t < NBUCK) ? bhist[t] : 0;
    sh[t] = v;
    __syncthreads();
    for (int o = 1; o < 256; o <<= 1) {
        int y = (t >= o) ? sh[t - o] : 0;
        __syncthreads();
        sh[t] += y;
        __syncthreads();
    }
    if (t < NBUCK) { int e = sh[t] - v; boffs[t] = e; bcursor[t] = e; }
    if (t == 0) { boffs[NBUCK] = NE; offs[NN] = NE; }
}

// Pass A3: scatter (src,dst) into bucket regions (196 hot write streams)
__global__ void k_bscatter(const int* __restrict__ src, const int* __restrict__ dst,
                           int* __restrict__ bcursor, int2* __restrict__ eb) {
    int i = blockIdx.x * blockDim.x + threadIdx.x;
    if (i < NE) {
        int d = dst[i];
        int p = atomicAdd(&bcursor[d >> 9], 1);
        eb[p] = make_int2(src[i], d);
    }
}

// Pass B: per-bucket counting sort -> offs (sequential) + csr (L2-local writes)
__global__ __launch_bounds__(512) void k_bsort(const int2* __restrict__ eb,
                                               const int* __restrict__ boffs,
                                               int* __restrict__ offs,
                                               int* __restrict__ csr) {
    __shared__ int hist[512];
    __shared__ int sc[512];
    int b = blockIdx.x, t = threadIdx.x;
    int beg = boffs[b], end = boffs[b + 1];
    hist[t] = 0;
    __syncthreads();
    for (int i = beg + t; i < end; i += 512)
        atomicAdd(&hist[eb[i].y & 511], 1);
    __syncthreads();
    int v = hist[t];
    sc[t] = v;
    __syncthreads();
    for (int o = 1; o < 512; o <<= 1) {
        int y = (t >= o) ? sc[t - o] : 0;
        __syncthreads();
        sc[t] += y;
        __syncthreads();
    }
    int mypos = beg + sc[t] - v;          // exclusive scan + bucket base
    int gd = b * 512 + t;
    if (gd < NN) offs[gd] = mypos;
    __syncthreads();
    hist[t] = mypos;                       // reuse as cursor
    __syncthreads();
    for (int i = beg + t; i < end; i += 512) {
        int2 e = eb[i];
        int p = atomicAdd(&hist[e.y & 511], 1);
        csr[p] = e.x;
    }
}

// ---------------- small precomputes ------------------------------------------
__global__ void k_prep_p1(const float* __restrict__ W1, const float* __restrict__ as1,
                          const float* __restrict__ ad1, float* __restrict__ ps1,
                          float* __restrict__ pd1) {
    int t = threadIdx.x;
    int h = t >> 6, cc = t & 63;
    float avs = as1[h * 64 + cc], avd = ad1[h * 64 + cc];
    for (int k = 0; k < 3; ++k) {
        float w = W1[k * 256 + h * 64 + cc];
        float vs = w * avs, vd = w * avd;
        #pragma unroll
        for (int m = 1; m < 64; m <<= 1) { vs += __shfl_xor(vs, m, 64); vd += __shfl_xor(vd, m, 64); }
        if (cc == 0) { ps1[h * 4 + k] = vs; pd1[h * 4 + k] = vd; }
    }
}

// Bt[c][vk], vk: 0-255 = hi(W2[vk][c]), 256-511 = lo(W2[vk-256][c])
__global__ void k_prep_bt(const float* __restrict__ W2, unsigned short* __restrict__ Bt) {
    int vk = blockIdx.x, c = threadIdx.x;
    float v = W2[(size_t)(vk & 255) * HC + c];
    unsigned short hi = f2bf(v);
    unsigned short o = (vk < 256) ? hi : f2bf(v - bf2f(hi));
    Bt[(size_t)c * 512 + vk] = o;
}

// ---------------- layer-1 aggregation: 16-lane group per node ----------------
__global__ __launch_bounds__(256) void k_agg1(
    const float* __restrict__ x, const float* __restrict__ W1,
    const float* __restrict__ ps1, const float* __restrict__ pd1,
    const int* __restrict__ offs, const int* __restrict__ csr,
    const float* __restrict__ b1, unsigned short* __restrict__ zh) {
    __shared__ float Y[16][16];
    int t = threadIdx.x;
    int g = t >> 4, l16 = t & 15;
    int d = blockIdx.x * 16 + g;          // NN = 16*6250 exactly: always valid
    float ps[4][3], pd[4][3];
    #pragma unroll
    for (int h = 0; h < 4; ++h) {
        ps[h][0] = ps1[h * 4 + 0]; ps[h][1] = ps1[h * 4 + 1]; ps[h][2] = ps1[h * 4 + 2];
        pd[h][0] = pd1[h * 4 + 0]; pd[h][1] = pd1[h * 4 + 1]; pd[h][2] = pd1[h * 4 + 2];
    }
    float xd0 = x[d * 3], xd1 = x[d * 3 + 1], xd2 = x[d * 3 + 2];
    float ald[4];
    #pragma unroll
    for (int h = 0; h < 4; ++h) ald[h] = xd0 * pd[h][0] + xd1 * pd[h][1] + xd2 * pd[h][2];
    float S[4] = {0.f, 0.f, 0.f, 0.f};
    float X0[4] = {0.f, 0.f, 0.f, 0.f}, X1[4] = {0.f, 0.f, 0.f, 0.f}, X2[4] = {0.f, 0.f, 0.f, 0.f};
    int beg = offs[d], end = offs[d + 1];
    for (int idx = beg + l16; idx < end; idx += 16) {
        int sn = csr[idx] * 3;
        float a0 = x[sn], a1 = x[sn + 1], a2 = x[sn + 2];
        #pragma unroll
        for (int h = 0; h < 4; ++h) {
            float e = a0 * ps[h][0] + a1 * ps[h][1] + a2 * ps[h][2] + ald[h];
            e = e > 0.f ? e : 0.2f * e;
            float p = __expf(e);
            S[h] += p; X0[h] += p * a0; X1[h] += p * a1; X2[h] += p * a2;
        }
    }
    if (l16 == 0) {   // self-loop contribution
        #pragma unroll
        for (int h = 0; h < 4; ++h) {
            float e = xd0 * ps[h][0] + xd1 * ps[h][1] + xd2 * ps[h][2] + ald[h];
            e = e > 0.f ? e : 0.2f * e;
            float p = __expf(e);
            S[h] += p; X0[h] += p * xd0; X1[h] += p * xd1; X2[h] += p * xd2;
        }
    }
    #pragma unroll
    for (int m = 1; m < 16; m <<= 1) {
        #pragma unroll
        for (int h = 0; h < 4; ++h) {
            S[h] += __shfl_xor(S[h], m, 64);
            X0[h] += __shfl_xor(X0[h], m, 64);
            X1[h] += __shfl_xor(X1[h], m, 64);
            X2[h] += __shfl_xor(X2[h], m, 64);
        }
    }
    if (l16 == 0) {
        *(float4*)&Y[g][0]  = make_float4(S[0], S[1], S[2], S[3]);
        *(float4*)&Y[g][4]  = make_float4(X0[0], X0[1], X0[2], X0[3]);
        *(float4*)&Y[g][8]  = make_float4(X1[0], X1[1], X1[2], X1[3]);
        *(float4*)&Y[g][12] = make_float4(X2[0], X2[1], X2[2], X2[3]);
    }
    __syncthreads();
    // phase 2: one wave per node, 4 rounds
    int lane = t & 63, w = t >> 6;
    int head = lane >> 4, c = lane << 2;
    float4 w0 = ld4(W1 + c), w1 = ld4(W1 + 256 + c), w2 = ld4(W1 + 512 + c);
    float4 bv = ld4(b1 + c);
    #pragma unroll
    for (int rr = 0; rr < 4; ++rr) {
        int g2 = w * 4 + rr;
        int d2 = blockIdx.x * 16 + g2;
        float inv = 1.f / Y[g2][head];
        float Y0 = Y[g2][4 + head] * inv;
        float Y1 = Y[g2][8 + head] * inv;
        float Y2 = Y[g2][12 + head] * inv;
        float4 z;
        z.x = fmaxf(Y0 * w0.x + Y1 * w1.x + Y2 * w2.x + bv.x, 0.f);
        z.y = fmaxf(Y0 * w0.y + Y1 * w1.y + Y2 * w2.y + bv.y, 0.f);
        z.z = fmaxf(Y0 * w0.z + Y1 * w1.z + Y2 * w2.z + bv.z, 0.f);
        z.w = fmaxf(Y0 * w0.w + Y1 * w1.w + Y2 * w2.w + bv.w, 0.f);
        ushort4 hi;
        hi.x = f2bf(z.x); hi.y = f2bf(z.y); hi.z = f2bf(z.z); hi.w = f2bf(z.w);
        *(ushort4*)(zh + (size_t)d2 * HC + c) = hi;
    }
}

// ---------------- GEMM2 via bf16 MFMA (zh@Wh + zh@Wl) + fused al2 logits -----
__global__ __launch_bounds__(512) void k_gemm2_mfma(
    const unsigned short* __restrict__ zh, const unsigned short* __restrict__ Bt,
    const float* __restrict__ a_s, const float* __restrict__ a_d,
    unsigned short* __restrict__ h2bf, float* __restrict__ alS2,
    float* __restrict__ alD2) {
    __shared__ __align__(16) unsigned short As[128 * 64];
    __shared__ __align__(16) unsigned short Bs[256 * 64];
    int t = threadIdx.x;
    int l = t & 63, w = t >> 6;
    int wm = w >> 2, wn = w & 3;
    int lr = l & 15, lk = l >> 4;
    int row0 = blockIdx.x * 128;

    f32x4 acc[4][4];
    f32x4 z4 = {0.f, 0.f, 0.f, 0.f};
    #pragma unroll
    for (int i = 0; i < 4; ++i)
        #pragma unroll
        for (int j = 0; j < 4; ++j) acc[i][j] = z4;

    int sa_row = t >> 2, sa_q = t & 3;
    const unsigned short* zrow = zh + (size_t)(row0 + sa_row) * HC;
    bool a_ok = (row0 + sa_row) < NN;
    int sb_col = t >> 1, sb_h = t & 1;
    const unsigned short* btrow = Bt + (size_t)sb_col * 512;

    for (int kt = 0; kt < 8; ++kt) {
        int ksb = kt * 64;
        int acol0 = ksb & 255;
        uint4 av0 = make_uint4(0, 0, 0, 0), av1 = make_uint4(0, 0, 0, 0);
        if (a_ok) {
            av0 = *(const uint4*)(zrow + acol0 + sa_q * 16);
            av1 = *(const uint4*)(zrow + acol0 + sa_q * 16 + 8);
        }
        int rs = sa_row * 64;
        *(uint4*)&As[rs + ((2 * sa_q) ^ (sa_row & 7)) * 8] = av0;
        *(uint4*)&As[rs + ((2 * sa_q + 1) ^ (sa_row & 7)) * 8] = av1;
        const unsigned short* bsrc = btrow + ksb + sb_h * 32;
        int cs = sb_col * 64;
        #pragma unroll
        for (int j = 0; j < 4; ++j) {
            uint4 bv = *(const uint4*)(bsrc + j * 8);
            *(uint4*)&Bs[cs + ((sb_h * 4 + j) ^ (sb_col & 7)) * 8] = bv;
        }
        __syncthreads();
        #pragma unroll
        for (int s = 0; s < 2; ++s) {
            short8 af[4], bfr[4];
            #pragma unroll
            for (int fi = 0; fi < 4; ++fi) {
                int row = wm * 64 + fi * 16 + lr;
                int kg = (s * 4 + lk) ^ (row & 7);
                af[fi] = *(const short8*)&As[row * 64 + kg * 8];
            }
            #pragma unroll
            for (int bj = 0; bj < 4; ++bj) {
                int col = wn * 64 + bj * 16 + lr;
                int kg = (s * 4 + lk) ^ (col & 7);
                bfr[bj] = *(const short8*)&Bs[col * 64 + kg * 8];
            }
            #pragma unroll
            for (int fi = 0; fi < 4; ++fi)
                #pragma unroll
                for (int bj = 0; bj < 4; ++bj)
                    acc[fi][bj] = __builtin_amdgcn_mfma_f32_16x16x32_bf16(af[fi], bfr[bj], acc[fi][bj], 0, 0, 0);
        }
        __syncthreads();
    }

    // epilogue: bf16 h2 store + per-head logits (head == wn, reduce over lr)
    float asr[4], adr[4];
    #pragma unroll
    for (int bj = 0; bj < 4; ++bj) {
        int cc = wn * 64 + bj * 16 + lr;
        asr[bj] = a_s[cc];
        adr[bj] = a_d[cc];
    }
    #pragma unroll
    for (int fi = 0; fi < 4; ++fi) {
        #pragma unroll
        for (int r = 0; r < 4; ++r) {
            int grow = row0 + wm * 64 + fi * 16 + lk * 4 + r;
            bool ok = grow < NN;
            float ps = 0.f, pd = 0.f;
            #pragma unroll
            for (int bj = 0; bj < 4; ++bj) {
                float vv = acc[fi][bj][r];
                if (ok) h2bf[(size_t)grow * HC + wn * 64 + bj * 16 + lr] = f2bf(vv);
                ps += vv * asr[bj];
                pd += vv * adr[bj];
            }
            #pragma unroll
            for (int mm = 1; mm < 16; mm <<= 1) {
                ps += __shfl_xor(ps, mm, 64);
                pd += __shfl_xor(pd, mm, 64);
            }
            if (ok && lr == 0) {
                alS2[grow * 4 + wn] = ps;
                alD2[grow * 4 + wn] = pd;
            }
        }
    }
}

// ---------------- edge-weight precompute, node-parallel ----------------------
__global__ __launch_bounds__(256) void k_prep_p(
    const float* __restrict__ alS2, const float* __restrict__ alD2,
    const int* __restrict__ offs, const int* __restrict__ csr,
    float* __restrict__ pw) {
    int gt = blockIdx.x * blockDim.x + threadIdx.x;
    int d = gt >> 4;                       // NN = 16*6250: always valid
    int l16 = threadIdx.x & 15;
    int head = l16 & 3;
    int eo = l16 >> 2;                     // edge offset within 4-edge chunk
    float ad = alD2[d * 4 + head];
    int beg = offs[d], end = offs[d + 1];
    for (int idx = beg + eo; idx < end; idx += 4) {
        int sn = csr[idx];
        float e = alS2[sn * 4 + head] + ad;
        e = e > 0.f ? e : 0.2f * e;
        pw[(size_t)idx * 4 + head] = __expf(e);
    }
}

// ---------------- layer-2 aggregation: 16-lane group per node ----------------
__global__ __launch_bounds__(256) void k_agg2(
    const unsigned short* __restrict__ h2bf, const float* __restrict__ alS2,
    const float* __restrict__ alD2, const int* __restrict__ offs,
    const int* __restrict__ csr, const float* __restrict__ pw,
    const float* __restrict__ b2, const float* __restrict__ fcw,
    const float* __restrict__ fcb, float* __restrict__ out) {
    int gt = blockIdx.x * blockDim.x + threadIdx.x;
    int d = gt >> 4;                       // NN = 16*6250: always valid
    int l16 = threadIdx.x & 15;
    int head = l16 >> 2;
    int cb = l16 * 16;                     // this lane's 16 channels
    float e0 = alS2[d * 4 + head] + alD2[d * 4 + head];
    e0 = e0 > 0.f ? e0 : 0.2f * e0;
    float s = __expf(e0);
    float acc[16], f[16];
    {
        const uint4* rp = (const uint4*)(h2bf + (size_t)d * HC + cb);
        uint4 r0 = rp[0], r1 = rp[1];
        unpack8(r0, f); unpack8(r1, f + 8);
        #pragma unroll
        for (int j = 0; j < 16; ++j) acc[j] = s * f[j];
    }
    int beg = offs[d], end = offs[d + 1];
    if (beg < end) {
        int i1 = (beg + 1 < end) ? beg + 1 : beg;
        int sn0 = csr[beg];
        float pv0 = pw[(size_t)beg * 4 + head];
        const uint4* rp0 = (const uint4*)(h2bf + (size_t)sn0 * HC + cb);
        uint4 a0 = rp0[0], b0 = rp0[1];
        int sn1 = csr[i1];
        float pv1 = (beg + 1 < end) ? pw[(size_t)(beg + 1) * 4 + head] : 0.f;
        const uint4* rp1 = (const uint4*)(h2bf + (size_t)sn1 * HC + cb);
        uint4 a1 = rp1[0], b1v = rp1[1];
        for (int i = beg; i < end; ++i) {
            int nx = i + 2;
            bool okn = nx < end;
            int snn = okn ? csr[nx] : sn0;
            float pvn = okn ? pw[(size_t)nx * 4 + head] : 0.f;
            const uint4* rpn = (const uint4*)(h2bf + (size_t)snn * HC + cb);
            uint4 an = rpn[0], bn = rpn[1];
            unpack8(a0, f); unpack8(b0, f + 8);
            s += pv0;
            #pragma unroll
            for (int j = 0; j < 16; ++j) acc[j] += pv0 * f[j];
            a0 = a1; b0 = b1v; pv0 = pv1;
            a1 = an; b1v = bn; pv1 = pvn;
        }
    }
    float inv = 1.f / (s + 1e-16f);
    float p0 = 0.f, p1 = 0.f;
    #pragma unroll
    for (int q = 0; q < 4; ++q) {
        float4 bv = ld4(b2 + cb + q * 4);
        float4 fa = ld4(fcw + (cb + q * 4) * 2);
        float4 fb = ld4(fcw + (cb + q * 4) * 2 + 4);
        float o0 = fmaxf(acc[q * 4 + 0] * inv + bv.x, 0.f);
        float o1 = fmaxf(acc[q * 4 + 1] * inv + bv.y, 0.f);
        float o2 = fmaxf(acc[q * 4 + 2] * inv + bv.z, 0.f);
        float o3 = fmaxf(acc[q * 4 + 3] * inv + bv.w, 0.f);
        p0 += o0 * fa.x + o1 * fa.z + o2 * fb.x + o3 * fb.z;
        p1 += o0 * fa.y + o1 * fa.w + o2 * fb.y + o3 * fb.w;
    }
    #pragma unroll
    for (int mm = 1; mm < 16; mm <<= 1) {
        p0 += __shfl_xor(p0, mm, 64);
        p1 += __shfl_xor(p1, mm, 64);
    }
    if (l16 == 0) {
        out[d * 2 + 0] = p0 + fcb[0];
        out[d * 2 + 1] = p1 + fcb[1];
    }
}

extern "C" void kernel_launch(void* const* d_in, const int* in_sizes, int n_in,
                              void* d_out, int out_size, void* d_ws, size_t ws_size,
                              hipStream_t stream) {
    const float* x   = (const float*)d_in[0];
    const int*   ei  = (const int*)d_in[1];
    const float* W1  = (const float*)d_in[2];
    const float* as1 = (const float*)d_in[3];
    const float* ad1 = (const float*)d_in[4];
    const float* b1  = (const float*)d_in[5];
    const float* W2  = (const float*)d_in[6];
    const float* as2 = (const float*)d_in[7];
    const float* ad2 = (const float*)d_in[8];
    const float* b2  = (const float*)d_in[9];
    const float* fcw = (const float*)d_in[10];
    const float* fcb = (const float*)d_in[11];
    float* out = (float*)d_out;

    char* p = (char*)d_ws;
    unsigned short* zh   = (unsigned short*)p; p += (size_t)NN * HC * 2;   // 51.2MB
    unsigned short* h2bf = (unsigned short*)p; p += (size_t)NN * HC * 2;   // 51.2MB
    float* alS2 = (float*)p; p += (size_t)NN * 4 * 4;
    float* alD2 = (float*)p; p += (size_t)NN * 4 * 4;
    float* ps1  = (float*)p; p += 256;
    float* pd1  = (float*)p; p += 256;
    unsigned short* Bt = (unsigned short*)p; p += (size_t)256 * 512 * 2;   // 256KB
    int* offs   = (int*)p;   p += (size_t)(NN + 2) * 4;
    int* csr    = (int*)p;   p += (size_t)NE * 4;
    int2* eb    = (int2*)p;  p += (size_t)NE * 8;
    float* pw   = (float*)p; p += (size_t)NE * 4 * 4;
    int* bhist  = (int*)p;   p += 1024;
    int* boffs  = (int*)p;   p += 1024;
    int* bcursor= (int*)p;   p += 1024;

    const int* e_src = ei;
    const int* e_dst = ei + NE;

    hipMemsetAsync(bhist, 0, NBUCK * sizeof(int), stream);
    k_bhist<<<(NE + 2047) / 2048, 256, 0, stream>>>(e_dst, bhist);
    k_bscan<<<1, 256, 0, stream>>>(bhist, boffs, bcursor, offs);
    k_bscatter<<<(NE + 255) / 256, 256, 0, stream>>>(e_src, e_dst, bcursor, eb);
    k_bsort<<<NBUCK, 512, 0, stream>>>(eb, boffs, offs, csr);

    k_prep_bt<<<512, 256, 0, stream>>>(W2, Bt);
    k_prep_p1<<<1, 256, 0, stream>>>(W1, as1, ad1, ps1, pd1);

    k_agg1<<<NN / 16, 256, 0, stream>>>(x, W1, ps1, pd1, offs, csr, b1, zh);
    k_gemm2_mfma<<<(NN + 127) / 128, 512, 0, stream>>>(zh, Bt, as2, ad2, h2bf, alS2, alD2);
    k_prep_p<<<NN / 16, 256, 0, stream>>>(alS2, alD2, offs, csr, pw);
    k_agg2<<<NN / 16, 256, 0, stream>>>(h2bf, alS2, alD2, offs, csr, pw, b2,
                                        fcw, fcb, out);
}

// Round 11
// 309.044 us; speedup vs baseline: 3.8172x; 3.8172x over previous
//
#include <hip/hip_runtime.h>

#define NN 100000
#define NE 1600000
#define HC 256
#define NBUCK 391    // ceil(NN/256) buckets of 256 dsts
#define CHUNK 8192   // edges per bscatter block

typedef __attribute__((ext_vector_type(8))) short short8;
typedef __attribute__((ext_vector_type(4))) float f32x4;

__device__ __forceinline__ float4 ld4(const float* p) { return *(const float4*)p; }
__device__ __forceinline__ unsigned short f2bf(float f) {
    unsigned u = __float_as_uint(f);
    return (unsigned short)((u + 0x7fffu + ((u >> 16) & 1u)) >> 16);
}
__device__ __forceinline__ float bf2f(unsigned short h) { return __uint_as_float(((unsigned)h) << 16); }

// unpack 8 bf16 (uint4) -> 8 f32
__device__ __forceinline__ void unpack8(uint4 v, float* f) {
    f[0] = __uint_as_float(v.x << 16); f[1] = __uint_as_float(v.x & 0xffff0000u);
    f[2] = __uint_as_float(v.y << 16); f[3] = __uint_as_float(v.y & 0xffff0000u);
    f[4] = __uint_as_float(v.z << 16); f[5] = __uint_as_float(v.z & 0xffff0000u);
    f[6] = __uint_as_float(v.w << 16); f[7] = __uint_as_float(v.w & 0xffff0000u);
}

// ---------------- CSR build: bucketed two-pass sort, LDS-binned scatter ------
__global__ __launch_bounds__(256) void k_bhist(const int* __restrict__ dst,
                                               int* __restrict__ bhist) {
    __shared__ int h[NBUCK];
    int t = threadIdx.x;
    for (int j = t; j < NBUCK; j += 256) h[j] = 0;
    __syncthreads();
    int base = blockIdx.x * 2048;
    int lim = min(base + 2048, NE);
    for (int i = base + t; i < lim; i += 256)
        atomicAdd(&h[dst[i] >> 8], 1);
    __syncthreads();
    for (int j = t; j < NBUCK; j += 256) if (h[j]) atomicAdd(&bhist[j], h[j]);
}

__global__ void k_bscan(const int* __restrict__ bhist, int* __restrict__ boffs,
                        int* __restrict__ bcursor, int* __restrict__ offs) {
    __shared__ int sh[512];
    int t = threadIdx.x;
    int v = (t < NBUCK) ? bhist[t] : 0;
    sh[t] = v;
    __syncthreads();
    for (int o = 1; o < 512; o <<= 1) {
        int y = (t >= o) ? sh[t - o] : 0;
        __syncthreads();
        sh[t] += y;
        __syncthreads();
    }
    if (t < NBUCK) { int e = sh[t] - v; boffs[t] = e; bcursor[t] = e; }
    if (t == 0) { boffs[NBUCK] = NE; offs[NN] = NE; }
}

// LDS-binned scatter: 1 global atomic per (block,bucket), dense write runs
__global__ __launch_bounds__(256) void k_bscatter2(
    const int* __restrict__ src, const int* __restrict__ dst,
    int* __restrict__ bcursor, int2* __restrict__ eb) {
    __shared__ int lh[NBUCK];
    __shared__ unsigned short lrank[CHUNK];
    int t = threadIdx.x;
    int base = blockIdx.x * CHUNK;
    int lim = min(base + CHUNK, NE);
    for (int j = t; j < NBUCK; j += 256) lh[j] = 0;
    __syncthreads();
    for (int i = base + t; i < lim; i += 256)
        lrank[i - base] = (unsigned short)atomicAdd(&lh[dst[i] >> 8], 1);
    __syncthreads();
    for (int j = t; j < NBUCK; j += 256) {
        int c = lh[j];
        lh[j] = c ? atomicAdd(&bcursor[j], c) : 0;
    }
    __syncthreads();
    for (int i = base + t; i < lim; i += 256) {
        int d = dst[i];
        int p = lh[d >> 8] + lrank[i - base];
        eb[p] = make_int2(src[i], d);
    }
}

// per-bucket counting sort -> offs (sequential) + csr (L2-local writes)
__global__ __launch_bounds__(256) void k_bsort(const int2* __restrict__ eb,
                                               const int* __restrict__ boffs,
                                               int* __restrict__ offs,
                                               int* __restrict__ csr) {
    __shared__ int hist[256];
    __shared__ int sc[256];
    int b = blockIdx.x, t = threadIdx.x;
    int beg = boffs[b], end = boffs[b + 1];
    hist[t] = 0;
    __syncthreads();
    for (int i = beg + t; i < end; i += 256)
        atomicAdd(&hist[eb[i].y & 255], 1);
    __syncthreads();
    int v = hist[t];
    sc[t] = v;
    __syncthreads();
    for (int o = 1; o < 256; o <<= 1) {
        int y = (t >= o) ? sc[t - o] : 0;
        __syncthreads();
        sc[t] += y;
        __syncthreads();
    }
    int mypos = beg + sc[t] - v;
    int gd = b * 256 + t;
    if (gd < NN) offs[gd] = mypos;
    __syncthreads();
    hist[t] = mypos;                       // reuse as cursor
    __syncthreads();
    for (int i = beg + t; i < end; i += 256) {
        int2 e = eb[i];
        int p = atomicAdd(&hist[e.y & 255], 1);
        csr[p] = e.x;
    }
}

// ---------------- small precomputes ------------------------------------------
__global__ void k_prep_p1(const float* __restrict__ W1, const float* __restrict__ as1,
                          const float* __restrict__ ad1, float* __restrict__ ps1,
                          float* __restrict__ pd1) {
    int t = threadIdx.x;
    int h = t >> 6, cc = t & 63;
    float avs = as1[h * 64 + cc], avd = ad1[h * 64 + cc];
    for (int k = 0; k < 3; ++k) {
        float w = W1[k * 256 + h * 64 + cc];
        float vs = w * avs, vd = w * avd;
        #pragma unroll
        for (int m = 1; m < 64; m <<= 1) { vs += __shfl_xor(vs, m, 64); vd += __shfl_xor(vd, m, 64); }
        if (cc == 0) { ps1[h * 4 + k] = vs; pd1[h * 4 + k] = vd; }
    }
}

// Bt[c][vk], vk: 0-255 = hi(W2[vk][c]), 256-511 = lo(W2[vk-256][c])
__global__ void k_prep_bt(const float* __restrict__ W2, unsigned short* __restrict__ Bt) {
    int vk = blockIdx.x, c = threadIdx.x;
    float v = W2[(size_t)(vk & 255) * HC + c];
    unsigned short hi = f2bf(v);
    unsigned short o = (vk < 256) ? hi : f2bf(v - bf2f(hi));
    Bt[(size_t)c * 512 + vk] = o;
}

// ---------------- layer-1 aggregation: 16-lane group per node ----------------
__global__ __launch_bounds__(256) void k_agg1(
    const float* __restrict__ x, const float* __restrict__ W1,
    const float* __restrict__ ps1, const float* __restrict__ pd1,
    const int* __restrict__ offs, const int* __restrict__ csr,
    const float* __restrict__ b1, unsigned short* __restrict__ zh) {
    __shared__ float Y[16][16];
    int t = threadIdx.x;
    int g = t >> 4, l16 = t & 15;
    int d = blockIdx.x * 16 + g;          // NN = 16*6250 exactly: always valid
    float ps[4][3], pd[4][3];
    #pragma unroll
    for (int h = 0; h < 4; ++h) {
        ps[h][0] = ps1[h * 4 + 0]; ps[h][1] = ps1[h * 4 + 1]; ps[h][2] = ps1[h * 4 + 2];
        pd[h][0] = pd1[h * 4 + 0]; pd[h][1] = pd1[h * 4 + 1]; pd[h][2] = pd1[h * 4 + 2];
    }
    float xd0 = x[d * 3], xd1 = x[d * 3 + 1], xd2 = x[d * 3 + 2];
    float ald[4];
    #pragma unroll
    for (int h = 0; h < 4; ++h) ald[h] = xd0 * pd[h][0] + xd1 * pd[h][1] + xd2 * pd[h][2];
    float S[4] = {0.f, 0.f, 0.f, 0.f};
    float X0[4] = {0.f, 0.f, 0.f, 0.f}, X1[4] = {0.f, 0.f, 0.f, 0.f}, X2[4] = {0.f, 0.f, 0.f, 0.f};
    int beg = offs[d], end = offs[d + 1];
    for (int idx = beg + l16; idx < end; idx += 16) {
        int sn = csr[idx] * 3;
        float a0 = x[sn], a1 = x[sn + 1], a2 = x[sn + 2];
        #pragma unroll
        for (int h = 0; h < 4; ++h) {
            float e = a0 * ps[h][0] + a1 * ps[h][1] + a2 * ps[h][2] + ald[h];
            e = e > 0.f ? e : 0.2f * e;
            float p = __expf(e);
            S[h] += p; X0[h] += p * a0; X1[h] += p * a1; X2[h] += p * a2;
        }
    }
    if (l16 == 0) {   // self-loop contribution
        #pragma unroll
        for (int h = 0; h < 4; ++h) {
            float e = xd0 * ps[h][0] + xd1 * ps[h][1] + xd2 * ps[h][2] + ald[h];
            e = e > 0.f ? e : 0.2f * e;
            float p = __expf(e);
            S[h] += p; X0[h] += p * xd0; X1[h] += p * xd1; X2[h] += p * xd2;
        }
    }
    #pragma unroll
    for (int m = 1; m < 16; m <<= 1) {
        #pragma unroll
        for (int h = 0; h < 4; ++h) {
            S[h] += __shfl_xor(S[h], m, 64);
            X0[h] += __shfl_xor(X0[h], m, 64);
            X1[h] += __shfl_xor(X1[h], m, 64);
            X2[h] += __shfl_xor(X2[h], m, 64);
        }
    }
    if (l16 == 0) {
        *(float4*)&Y[g][0]  = make_float4(S[0], S[1], S[2], S[3]);
        *(float4*)&Y[g][4]  = make_float4(X0[0], X0[1], X0[2], X0[3]);
        *(float4*)&Y[g][8]  = make_float4(X1[0], X1[1], X1[2], X1[3]);
        *(float4*)&Y[g][12] = make_float4(X2[0], X2[1], X2[2], X2[3]);
    }
    __syncthreads();
    // phase 2: one wave per node, 4 rounds
    int lane = t & 63, w = t >> 6;
    int head = lane >> 4, c = lane << 2;
    float4 w0 = ld4(W1 + c), w1 = ld4(W1 + 256 + c), w2 = ld4(W1 + 512 + c);
    float4 bv = ld4(b1 + c);
    #pragma unroll
    for (int rr = 0; rr < 4; ++rr) {
        int g2 = w * 4 + rr;
        int d2 = blockIdx.x * 16 + g2;
        float inv = 1.f / Y[g2][head];
        float Y0 = Y[g2][4 + head] * inv;
        float Y1 = Y[g2][8 + head] * inv;
        float Y2 = Y[g2][12 + head] * inv;
        float4 z;
        z.x = fmaxf(Y0 * w0.x + Y1 * w1.x + Y2 * w2.x + bv.x, 0.f);
        z.y = fmaxf(Y0 * w0.y + Y1 * w1.y + Y2 * w2.y + bv.y, 0.f);
        z.z = fmaxf(Y0 * w0.z + Y1 * w1.z + Y2 * w2.z + bv.z, 0.f);
        z.w = fmaxf(Y0 * w0.w + Y1 * w1.w + Y2 * w2.w + bv.w, 0.f);
        ushort4 hi;
        hi.x = f2bf(z.x); hi.y = f2bf(z.y); hi.z = f2bf(z.z); hi.w = f2bf(z.w);
        *(ushort4*)(zh + (size_t)d2 * HC + c) = hi;
    }
}

// ---------------- GEMM2 via bf16 MFMA (zh@Wh + zh@Wl) + fused al2 logits -----
__global__ __launch_bounds__(512) void k_gemm2_mfma(
    const unsigned short* __restrict__ zh, const unsigned short* __restrict__ Bt,
    const float* __restrict__ a_s, const float* __restrict__ a_d,
    unsigned short* __restrict__ h2bf, float* __restrict__ alS2,
    float* __restrict__ alD2) {
    __shared__ __align__(16) unsigned short As[128 * 64];
    __shared__ __align__(16) unsigned short Bs[256 * 64];
    int t = threadIdx.x;
    int l = t & 63, w = t >> 6;
    int wm = w >> 2, wn = w & 3;
    int lr = l & 15, lk = l >> 4;
    int row0 = blockIdx.x * 128;

    f32x4 acc[4][4];
    f32x4 z4 = {0.f, 0.f, 0.f, 0.f};
    #pragma unroll
    for (int i = 0; i < 4; ++i)
        #pragma unroll
        for (int j = 0; j < 4; ++j) acc[i][j] = z4;

    int sa_row = t >> 2, sa_q = t & 3;
    const unsigned short* zrow = zh + (size_t)(row0 + sa_row) * HC;
    bool a_ok = (row0 + sa_row) < NN;
    int sb_col = t >> 1, sb_h = t & 1;
    const unsigned short* btrow = Bt + (size_t)sb_col * 512;

    for (int kt = 0; kt < 8; ++kt) {
        int ksb = kt * 64;
        int acol0 = ksb & 255;
        uint4 av0 = make_uint4(0, 0, 0, 0), av1 = make_uint4(0, 0, 0, 0);
        if (a_ok) {
            av0 = *(const uint4*)(zrow + acol0 + sa_q * 16);
            av1 = *(const uint4*)(zrow + acol0 + sa_q * 16 + 8);
        }
        int rs = sa_row * 64;
        *(uint4*)&As[rs + ((2 * sa_q) ^ (sa_row & 7)) * 8] = av0;
        *(uint4*)&As[rs + ((2 * sa_q + 1) ^ (sa_row & 7)) * 8] = av1;
        const unsigned short* bsrc = btrow + ksb + sb_h * 32;
        int cs = sb_col * 64;
        #pragma unroll
        for (int j = 0; j < 4; ++j) {
            uint4 bv = *(const uint4*)(bsrc + j * 8);
            *(uint4*)&Bs[cs + ((sb_h * 4 + j) ^ (sb_col & 7)) * 8] = bv;
        }
        __syncthreads();
        #pragma unroll
        for (int s = 0; s < 2; ++s) {
            short8 af[4], bfr[4];
            #pragma unroll
            for (int fi = 0; fi < 4; ++fi) {
                int row = wm * 64 + fi * 16 + lr;
                int kg = (s * 4 + lk) ^ (row & 7);
                af[fi] = *(const short8*)&As[row * 64 + kg * 8];
            }
            #pragma unroll
            for (int bj = 0; bj < 4; ++bj) {
                int col = wn * 64 + bj * 16 + lr;
                int kg = (s * 4 + lk) ^ (col & 7);
                bfr[bj] = *(const short8*)&Bs[col * 64 + kg * 8];
            }
            #pragma unroll
            for (int fi = 0; fi < 4; ++fi)
                #pragma unroll
                for (int bj = 0; bj < 4; ++bj)
                    acc[fi][bj] = __builtin_amdgcn_mfma_f32_16x16x32_bf16(af[fi], bfr[bj], acc[fi][bj], 0, 0, 0);
        }
        __syncthreads();
    }

    // epilogue: bf16 h2 store + per-head logits (head == wn, reduce over lr)
    float asr[4], adr[4];
    #pragma unroll
    for (int bj = 0; bj < 4; ++bj) {
        int cc = wn * 64 + bj * 16 + lr;
        asr[bj] = a_s[cc];
        adr[bj] = a_d[cc];
    }
    #pragma unroll
    for (int fi = 0; fi < 4; ++fi) {
        #pragma unroll
        for (int r = 0; r < 4; ++r) {
            int grow = row0 + wm * 64 + fi * 16 + lk * 4 + r;
            bool ok = grow < NN;
            float ps = 0.f, pd = 0.f;
            #pragma unroll
            for (int bj = 0; bj < 4; ++bj) {
                float vv = acc[fi][bj][r];
                if (ok) h2bf[(size_t)grow * HC + wn * 64 + bj * 16 + lr] = f2bf(vv);
                ps += vv * asr[bj];
                pd += vv * adr[bj];
            }
            #pragma unroll
            for (int mm = 1; mm < 16; mm <<= 1) {
                ps += __shfl_xor(ps, mm, 64);
                pd += __shfl_xor(pd, mm, 64);
            }
            if (ok && lr == 0) {
                alS2[grow * 4 + wn] = ps;
                alD2[grow * 4 + wn] = pd;
            }
        }
    }
}

// ---------------- edge-weight precompute, node-parallel ----------------------
__global__ __launch_bounds__(256) void k_prep_p(
    const float* __restrict__ alS2, const float* __restrict__ alD2,
    const int* __restrict__ offs, const int* __restrict__ csr,
    float* __restrict__ pw) {
    int gt = blockIdx.x * blockDim.x + threadIdx.x;
    int d = gt >> 4;                       // NN = 16*6250: always valid
    int l16 = threadIdx.x & 15;
    int head = l16 & 3;
    int eo = l16 >> 2;                     // edge offset within 4-edge chunk
    float ad = alD2[d * 4 + head];
    int beg = offs[d], end = offs[d + 1];
    for (int idx = beg + eo; idx < end; idx += 4) {
        int sn = csr[idx];
        float e = alS2[sn * 4 + head] + ad;
        e = e > 0.f ? e : 0.2f * e;
        pw[(size_t)idx * 4 + head] = __expf(e);
    }
}

// ---------------- layer-2 aggregation: 16-lane group per node ----------------
__global__ __launch_bounds__(256) void k_agg2(
    const unsigned short* __restrict__ h2bf, const float* __restrict__ alS2,
    const float* __restrict__ alD2, const int* __restrict__ offs,
    const int* __restrict__ csr, const float* __restrict__ pw,
    const float* __restrict__ b2, const float* __restrict__ fcw,
    const float* __restrict__ fcb, float* __restrict__ out) {
    int gt = blockIdx.x * blockDim.x + threadIdx.x;
    int d = gt >> 4;                       // NN = 16*6250: always valid
    int l16 = threadIdx.x & 15;
    int head = l16 >> 2;
    int cb = l16 * 16;                     // this lane's 16 channels
    float e0 = alS2[d * 4 + head] + alD2[d * 4 + head];
    e0 = e0 > 0.f ? e0 : 0.2f * e0;
    float s = __expf(e0);
    float acc[16], f[16];
    {
        const uint4* rp = (const uint4*)(h2bf + (size_t)d * HC + cb);
        uint4 r0 = rp[0], r1 = rp[1];
        unpack8(r0, f); unpack8(r1, f + 8);
        #pragma unroll
        for (int j = 0; j < 16; ++j) acc[j] = s * f[j];
    }
    int beg = offs[d], end = offs[d + 1];
    if (beg < end) {
        int i1 = (beg + 1 < end) ? beg + 1 : beg;
        int sn0 = csr[beg];
        float pv0 = pw[(size_t)beg * 4 + head];
        const uint4* rp0 = (const uint4*)(h2bf + (size_t)sn0 * HC + cb);
        uint4 a0 = rp0[0], b0 = rp0[1];
        int sn1 = csr[i1];
        float pv1 = (beg + 1 < end) ? pw[(size_t)(beg + 1) * 4 + head] : 0.f;
        const uint4* rp1 = (const uint4*)(h2bf + (size_t)sn1 * HC + cb);
        uint4 a1 = rp1[0], b1v = rp1[1];
        for (int i = beg; i < end; ++i) {
            int nx = i + 2;
            bool okn = nx < end;
            int snn = okn ? csr[nx] : sn0;
            float pvn = okn ? pw[(size_t)nx * 4 + head] : 0.f;
            const uint4* rpn = (const uint4*)(h2bf + (size_t)snn * HC + cb);
            uint4 an = rpn[0], bn = rpn[1];
            unpack8(a0, f); unpack8(b0, f + 8);
            s += pv0;
            #pragma unroll
            for (int j = 0; j < 16; ++j) acc[j] += pv0 * f[j];
            a0 = a1; b0 = b1v; pv0 = pv1;
            a1 = an; b1v = bn; pv1 = pvn;
        }
    }
    float inv = 1.f / (s + 1e-16f);
    float p0 = 0.f, p1 = 0.f;
    #pragma unroll
    for (int q = 0; q < 4; ++q) {
        float4 bv = ld4(b2 + cb + q * 4);
        float4 fa = ld4(fcw + (cb + q * 4) * 2);
        float4 fb = ld4(fcw + (cb + q * 4) * 2 + 4);
        float o0 = fmaxf(acc[q * 4 + 0] * inv + bv.x, 0.f);
        float o1 = fmaxf(acc[q * 4 + 1] * inv + bv.y, 0.f);
        float o2 = fmaxf(acc[q * 4 + 2] * inv + bv.z, 0.f);
        float o3 = fmaxf(acc[q * 4 + 3] * inv + bv.w, 0.f);
        p0 += o0 * fa.x + o1 * fa.z + o2 * fb.x + o3 * fb.z;
        p1 += o0 * fa.y + o1 * fa.w + o2 * fb.y + o3 * fb.w;
    }
    #pragma unroll
    for (int mm = 1; mm < 16; mm <<= 1) {
        p0 += __shfl_xor(p0, mm, 64);
        p1 += __shfl_xor(p1, mm, 64);
    }
    if (l16 == 0) {
        out[d * 2 + 0] = p0 + fcb[0];
        out[d * 2 + 1] = p1 + fcb[1];
    }
}

extern "C" void kernel_launch(void* const* d_in, const int* in_sizes, int n_in,
                              void* d_out, int out_size, void* d_ws, size_t ws_size,
                              hipStream_t stream) {
    const float* x   = (const float*)d_in[0];
    const int*   ei  = (const int*)d_in[1];
    const float* W1  = (const float*)d_in[2];
    const float* as1 = (const float*)d_in[3];
    const float* ad1 = (const float*)d_in[4];
    const float* b1  = (const float*)d_in[5];
    const float* W2  = (const float*)d_in[6];
    const float* as2 = (const float*)d_in[7];
    const float* ad2 = (const float*)d_in[8];
    const float* b2  = (const float*)d_in[9];
    const float* fcw = (const float*)d_in[10];
    const float* fcb = (const float*)d_in[11];
    float* out = (float*)d_out;

    char* p = (char*)d_ws;
    unsigned short* zh   = (unsigned short*)p; p += (size_t)NN * HC * 2;   // 51.2MB
    unsigned short* h2bf = (unsigned short*)p; p += (size_t)NN * HC * 2;   // 51.2MB
    float* alS2 = (float*)p; p += (size_t)NN * 4 * 4;
    float* alD2 = (float*)p; p += (size_t)NN * 4 * 4;
    float* ps1  = (float*)p; p += 256;
    float* pd1  = (float*)p; p += 256;
    unsigned short* Bt = (unsigned short*)p; p += (size_t)256 * 512 * 2;   // 256KB
    int* offs   = (int*)p;   p += (size_t)(NN + 2) * 4;
    int* csr    = (int*)p;   p += (size_t)NE * 4;
    int2* eb    = (int2*)p;  p += (size_t)NE * 8;
    float* pw   = (float*)p; p += (size_t)NE * 4 * 4;
    int* bhist  = (int*)p;   p += 2048;
    int* boffs  = (int*)p;   p += 2048;
    int* bcursor= (int*)p;   p += 2048;

    const int* e_src = ei;
    const int* e_dst = ei + NE;

    hipMemsetAsync(bhist, 0, NBUCK * sizeof(int), stream);
    k_bhist<<<(NE + 2047) / 2048, 256, 0, stream>>>(e_dst, bhist);
    k_bscan<<<1, 512, 0, stream>>>(bhist, boffs, bcursor, offs);
    k_bscatter2<<<(NE + CHUNK - 1) / CHUNK, 256, 0, stream>>>(e_src, e_dst, bcursor, eb);
    k_bsort<<<NBUCK, 256, 0, stream>>>(eb, boffs, offs, csr);

    k_prep_bt<<<512, 256, 0, stream>>>(W2, Bt);
    k_prep_p1<<<1, 256, 0, stream>>>(W1, as1, ad1, ps1, pd1);

    k_agg1<<<NN / 16, 256, 0, stream>>>(x, W1, ps1, pd1, offs, csr, b1, zh);
    k_gemm2_mfma<<<(NN + 127) / 128, 512, 0, stream>>>(zh, Bt, as2, ad2, h2bf, alS2, alD2);
    k_prep_p<<<NN / 16, 256, 0, stream>>>(alS2, alD2, offs, csr, pw);
    k_agg2<<<NN / 16, 256, 0, stream>>>(h2bf, alS2, alD2, offs, csr, pw, b2,
                                        fcw, fcb, out);
}